// Round 1
// baseline (401.273 us; speedup 1.0000x reference)
//
#include <hip/hip_runtime.h>
#include <hip/hip_bf16.h>

// Problem constants
#define N_NODES 4096
#define BATCH   128
#define DD      32           // D_IN == D_OUT
#define M_DIM   (BATCH * DD) // 4096  (m = b*32 + q)

typedef float  f32x4  __attribute__((ext_vector_type(4)));
typedef __bf16 bf16x8 __attribute__((ext_vector_type(8)));

// async global->LDS, 16 B per lane. LDS dest semantics: wave-uniform base + lane*16.
__device__ __forceinline__ void async_copy16(const void* g, void* l) {
    __builtin_amdgcn_global_load_lds(
        (const __attribute__((address_space(1))) unsigned int*)g,
        (__attribute__((address_space(3))) unsigned int*)l,
        16, 0, 0);
}

// ---------------------------------------------------------------------------
// Kernel 1: T[m=(b*32+q)][i] = sum_p x[b,i,p]*Wn[p][q]  (bf16, GEMM A layout)
//           U[b,i,q]         = sum_p x[b,i,p]*Ws[p][q]  (fp32, written to d_out)
// one thread per (b,i) row; W matrices staged in LDS (broadcast reads are free)
// ---------------------------------------------------------------------------
__global__ __launch_bounds__(256) void k_prep_tu(
    const float* __restrict__ x, const float* __restrict__ Wn,
    const float* __restrict__ Ws, __hip_bfloat16* __restrict__ T,
    float* __restrict__ out)
{
    __shared__ float WnS[DD * DD];
    __shared__ float WsS[DD * DD];
    const int tid = threadIdx.x;
#pragma unroll
    for (int r = 0; r < 4; ++r) {
        WnS[r * 256 + tid] = Wn[r * 256 + tid];
        WsS[r * 256 + tid] = Ws[r * 256 + tid];
    }
    __syncthreads();

    const int row = blockIdx.x * 256 + tid;  // row = b*4096 + i
    const int b   = row >> 12;
    const int i   = row & 4095;

    float xr[32];
    const float4* xp = (const float4*)(x + (size_t)row * 32);
#pragma unroll
    for (int v = 0; v < 8; ++v) {
        const float4 t = xp[v];
        xr[4 * v]     = t.x;
        xr[4 * v + 1] = t.y;
        xr[4 * v + 2] = t.z;
        xr[4 * v + 3] = t.w;
    }

#pragma unroll
    for (int qb = 0; qb < 8; ++qb) {
        float4 aT = make_float4(0.f, 0.f, 0.f, 0.f);
        float4 aU = make_float4(0.f, 0.f, 0.f, 0.f);
#pragma unroll
        for (int p = 0; p < 32; ++p) {
            const float  xv = xr[p];
            const float4 wn = *(const float4*)&WnS[p * 32 + qb * 4];
            const float4 ws = *(const float4*)&WsS[p * 32 + qb * 4];
            aT.x = fmaf(xv, wn.x, aT.x); aT.y = fmaf(xv, wn.y, aT.y);
            aT.z = fmaf(xv, wn.z, aT.z); aT.w = fmaf(xv, wn.w, aT.w);
            aU.x = fmaf(xv, ws.x, aU.x); aU.y = fmaf(xv, ws.y, aU.y);
            aU.z = fmaf(xv, ws.z, aU.z); aU.w = fmaf(xv, ws.w, aU.w);
        }
        // T writes: rows m = b*32 + qb*4 + {0..3}, contiguous over i per lane-group
        const size_t tb = ((size_t)(b * 32 + qb * 4)) * N_NODES + i;
        T[tb]            = __float2bfloat16(aT.x);
        T[tb + N_NODES]  = __float2bfloat16(aT.y);
        T[tb + 2*N_NODES]= __float2bfloat16(aT.z);
        T[tb + 3*N_NODES]= __float2bfloat16(aT.w);
        // U (self part, pre-relu) into d_out at [b][i][q]
        float4* up = (float4*)(out + (size_t)b * (N_NODES * DD) + (size_t)i * DD + qb * 4);
        *up = aU;
    }
}

// ---------------------------------------------------------------------------
// Kernel 2: adjT[j][i] = (bf16) adj[i][j]   — LDS 64x65 tile transpose
// ---------------------------------------------------------------------------
__global__ __launch_bounds__(256) void k_transpose_adj(
    const float* __restrict__ adj, __hip_bfloat16* __restrict__ adjT)
{
    __shared__ float ts[64][65];
    const int tid = threadIdx.x;
    const int cx  = tid & 63;
    const int cy  = tid >> 6;
    const int i0  = blockIdx.y << 6;
    const int j0  = blockIdx.x << 6;
#pragma unroll
    for (int r = 0; r < 16; ++r) {
        const int row = cy * 16 + r;
        ts[row][cx] = adj[(size_t)(i0 + row) * N_NODES + j0 + cx];
    }
    __syncthreads();
#pragma unroll
    for (int r = 0; r < 16; ++r) {
        const int row = cy * 16 + r;
        adjT[(size_t)(j0 + row) * N_NODES + i0 + cx] = __float2bfloat16(ts[cx][row]);
    }
}

// ---------------------------------------------------------------------------
// Kernel 3: C[m][j] = sum_i T[m][i] * adjT[j][i]   (4096^3 bf16 GEMM, m97 style)
//           out[b*131072 + j*32 + q] = relu(U + C),  m = b*32+q
// 128x128 tile, BK=32, 4 waves of 4x4 16x16x32 MFMA, global_load_lds width 16.
// ---------------------------------------------------------------------------
__global__ __launch_bounds__(256) void k_gemm_neigh(
    const __hip_bfloat16* __restrict__ A,   // T  [4096][4096]
    const __hip_bfloat16* __restrict__ BT,  // adjT [4096][4096]
    float* __restrict__ out)                // holds U; RMW + relu
{
    __shared__ alignas(16) __hip_bfloat16 As[128 * 32];
    __shared__ alignas(16) __hip_bfloat16 Bs[128 * 32];

    const int tid   = threadIdx.x;
    const int lane  = tid & 63;
    const int wave  = tid >> 6;
    const int bm    = blockIdx.y << 7;
    const int bn    = blockIdx.x << 7;
    const int waveM = (wave >> 1) << 6;
    const int waveN = (wave & 1) << 6;
    const int lr    = lane & 15;   // row (A) / col (B) within 16-tile
    const int lq    = lane >> 4;   // k-quad

    f32x4 acc[4][4] = {};

    // staging map: element e = tid*8 (+2048 for issue 1) -> row e/32, col e%32
    const int r0 = tid >> 2;
    const int c0 = (tid & 3) << 3;
    const __hip_bfloat16* ga = A  + (size_t)(bm + r0) * 4096 + c0;
    const __hip_bfloat16* gb = BT + (size_t)(bn + r0) * 4096 + c0;
    char* la = (char*)As + tid * 16;
    char* lb = (char*)Bs + tid * 16;

    for (int k0 = 0; k0 < 4096; k0 += 32) {
        async_copy16(ga + k0,                        la);
        async_copy16(ga + (size_t)64 * 4096 + k0,    la + 4096);
        async_copy16(gb + k0,                        lb);
        async_copy16(gb + (size_t)64 * 4096 + k0,    lb + 4096);
        __syncthreads();   // drains vmcnt -> LDS tiles complete

        bf16x8 af[4], bfr[4];
#pragma unroll
        for (int t = 0; t < 4; ++t) {
            af[t]  = *(const bf16x8*)&As[(waveM + t * 16 + lr) * 32 + lq * 8];
            bfr[t] = *(const bf16x8*)&Bs[(waveN + t * 16 + lr) * 32 + lq * 8];
        }
#pragma unroll
        for (int tm = 0; tm < 4; ++tm)
#pragma unroll
            for (int tn = 0; tn < 4; ++tn)
                acc[tm][tn] = __builtin_amdgcn_mfma_f32_16x16x32_bf16(
                    af[tm], bfr[tn], acc[tm][tn], 0, 0, 0);
        __syncthreads();   // all waves done reading LDS before next stage
    }

    // epilogue: C/D layout col=lane&15 (=j), row=quad*4+reg (=m); q=m&31 contiguous
#pragma unroll
    for (int tm = 0; tm < 4; ++tm) {
        const int gm0 = bm + waveM + tm * 16 + lq * 4;  // rows gm0..gm0+3
        const int b   = gm0 >> 5;
        const int q0  = gm0 & 31;                        // multiple of 4
#pragma unroll
        for (int tn = 0; tn < 4; ++tn) {
            const int gj = bn + waveN + tn * 16 + lr;
            float* p = out + (size_t)b * (N_NODES * DD) + (size_t)gj * DD + q0;
            const float4 u = *(const float4*)p;
            float4 v;
            v.x = fmaxf(acc[tm][tn][0] + u.x, 0.0f);
            v.y = fmaxf(acc[tm][tn][1] + u.y, 0.0f);
            v.z = fmaxf(acc[tm][tn][2] + u.z, 0.0f);
            v.w = fmaxf(acc[tm][tn][3] + u.w, 0.0f);
            *(float4*)p = v;
        }
    }
}

extern "C" void kernel_launch(void* const* d_in, const int* in_sizes, int n_in,
                              void* d_out, int out_size, void* d_ws, size_t ws_size,
                              hipStream_t stream) {
    const float* x   = (const float*)d_in[0];  // [128, 4096*32]
    const float* adj = (const float*)d_in[1];  // [4096, 4096]
    const float* Wn  = (const float*)d_in[2];  // [32, 32]
    const float* Ws  = (const float*)d_in[3];  // [32, 32]
    float* out = (float*)d_out;                // [128, 4096*32]

    // workspace: T bf16 (32 MB) | adjT bf16 (32 MB)
    __hip_bfloat16* T    = (__hip_bfloat16*)d_ws;
    __hip_bfloat16* adjT = T + (size_t)N_NODES * N_NODES;

    hipLaunchKernelGGL(k_prep_tu, dim3(BATCH * N_NODES / 256), dim3(256), 0, stream,
                       x, Wn, Ws, T, out);
    hipLaunchKernelGGL(k_transpose_adj, dim3(64, 64), dim3(256), 0, stream, adj, adjT);
    hipLaunchKernelGGL(k_gemm_neigh, dim3(32, 32), dim3(256), 0, stream, T, adjT, out);
}

// Round 2
// 368.098 us; speedup vs baseline: 1.0901x; 1.0901x over previous
//
#include <hip/hip_runtime.h>
#include <hip/hip_bf16.h>

// Problem constants
#define N_NODES 4096
#define BATCH   128
#define DD      32           // D_IN == D_OUT

typedef float  f32x4  __attribute__((ext_vector_type(4)));
typedef __bf16 bf16x8 __attribute__((ext_vector_type(8)));
typedef __bf16 bf16x4 __attribute__((ext_vector_type(4)));

// async global->LDS, 16 B per lane. LDS dest semantics: wave-uniform base + lane*16.
__device__ __forceinline__ void async_copy16(const void* g, void* l) {
    __builtin_amdgcn_global_load_lds(
        (const __attribute__((address_space(1))) unsigned int*)g,
        (__attribute__((address_space(3))) unsigned int*)l,
        16, 0, 0);
}

// ---------------------------------------------------------------------------
// Kernel 1 (MFMA): per 16-row tile of x3 [524288 x 32]:
//   T[m=(b*32+q)][i] = bf16( x @ Wn )   (GEMM A layout for kernel 3)
//   U[b][i][q]       = f32 ( x @ Ws )   (self part, pre-relu, into d_out)
// A-frag comes straight from global (row-major x matches A[m=lane&15][k=quad*8+j]);
// W-frags built once per wave. No LDS at all.
// ---------------------------------------------------------------------------
__global__ __launch_bounds__(256) void k_prep(
    const float* __restrict__ x, const float* __restrict__ Wn,
    const float* __restrict__ Ws, __hip_bfloat16* __restrict__ T,
    float* __restrict__ out)
{
    const int lane = threadIdx.x & 63;
    const int gw   = (blockIdx.x * 256 + threadIdx.x) >> 6;  // global wave id, 0..4095
    const int m    = lane & 15;   // A row / C col index
    const int quad = lane >> 4;   // k-quad

    // B fragments: B consumed as Bt[n][k] with n=lane&15, k=quad*8+j  ->  W[k*32+n]
    bf16x8 bn[2], bs[2];
#pragma unroll
    for (int h = 0; h < 2; ++h) {
        const int n = m + h * 16;
#pragma unroll
        for (int j = 0; j < 8; ++j) {
            const int k = quad * 8 + j;
            bn[h][j] = (__bf16)Wn[k * 32 + n];
            bs[h][j] = (__bf16)Ws[k * 32 + n];
        }
    }

    for (int t = gw; t < 32768; t += 4096) {       // 16-row tiles
        const int row0 = t << 4;                   // global row = b*4096 + i0
        const int b    = row0 >> 12;
        const int i0   = row0 & 4095;

        // A frag: x[row0+m][quad*8 .. +8] -> bf16x8 (32B/lane, coalesced in 2KB/wave)
        const float4* xp = (const float4*)(x + (size_t)(row0 + m) * DD + quad * 8);
        const float4 x0 = xp[0], x1 = xp[1];
        bf16x8 a;
        a[0] = (__bf16)x0.x; a[1] = (__bf16)x0.y; a[2] = (__bf16)x0.z; a[3] = (__bf16)x0.w;
        a[4] = (__bf16)x1.x; a[5] = (__bf16)x1.y; a[6] = (__bf16)x1.z; a[7] = (__bf16)x1.w;

        const f32x4 z = {};
        const f32x4 cT0 = __builtin_amdgcn_mfma_f32_16x16x32_bf16(a, bn[0], z, 0, 0, 0);
        const f32x4 cT1 = __builtin_amdgcn_mfma_f32_16x16x32_bf16(a, bn[1], z, 0, 0, 0);
        const f32x4 cU0 = __builtin_amdgcn_mfma_f32_16x16x32_bf16(a, bs[0], z, 0, 0, 0);
        const f32x4 cU1 = __builtin_amdgcn_mfma_f32_16x16x32_bf16(a, bs[1], z, 0, 0, 0);

        // C/D: col=lane&15 (=q within half), row=quad*4+reg (=i-local, 4 consecutive)
        bf16x4 t0, t1;
        t0[0] = (__bf16)cT0[0]; t0[1] = (__bf16)cT0[1]; t0[2] = (__bf16)cT0[2]; t0[3] = (__bf16)cT0[3];
        t1[0] = (__bf16)cT1[0]; t1[1] = (__bf16)cT1[1]; t1[2] = (__bf16)cT1[2]; t1[3] = (__bf16)cT1[3];
        *(bf16x4*)&T[((size_t)(b * 32 + m))      * N_NODES + i0 + quad * 4] = t0;
        *(bf16x4*)&T[((size_t)(b * 32 + m + 16)) * N_NODES + i0 + quad * 4] = t1;

        float* ub = out + (size_t)b * (N_NODES * DD) + (size_t)(i0 + quad * 4) * DD;
#pragma unroll
        for (int r = 0; r < 4; ++r) {
            ub[r * DD + m]      = cU0[r];
            ub[r * DD + m + 16] = cU1[r];
        }
    }
}

// ---------------------------------------------------------------------------
// Kernel 2: adjT[j][i] = (bf16) adj[i][j] — LDS 64x65 transpose, 16B packed stores.
// Store-phase LDS reads ts[il+k][jl]: bank=(il+k+jl)%32 -> max 2-way (free).
// ---------------------------------------------------------------------------
__global__ __launch_bounds__(256) void k_transpose_adj(
    const float* __restrict__ adj, __hip_bfloat16* __restrict__ adjT)
{
    __shared__ float ts[64][65];
    const int tid = threadIdx.x;
    const int cx  = tid & 63;
    const int cy  = tid >> 6;
    const int i0  = blockIdx.y << 6;
    const int j0  = blockIdx.x << 6;
#pragma unroll
    for (int r = 0; r < 16; ++r) {
        const int row = cy * 16 + r;
        ts[row][cx] = adj[(size_t)(i0 + row) * N_NODES + j0 + cx];
    }
    __syncthreads();
    const int il = (tid & 7) * 8;
    const int jb = tid >> 3;          // 0..31
#pragma unroll
    for (int rr = 0; rr < 2; ++rr) {
        const int jl = jb + rr * 32;
        bf16x8 v;
#pragma unroll
        for (int k = 0; k < 8; ++k) v[k] = (__bf16)ts[il + k][jl];
        *(bf16x8*)&adjT[(size_t)(j0 + jl) * N_NODES + i0 + il] = v;
    }
}

// ---------------------------------------------------------------------------
// Kernel 3: C[m][j] = sum_i T[m][i] * adjT[j][i]   (4096^3 bf16 GEMM, m97 style)
//           out[b*131072 + j*32 + q] = relu(U + C),  m = b*32+q
// 128x128 tile, BK=32, 4 waves of 4x4 16x16x32 MFMA, global_load_lds width 16.
// ---------------------------------------------------------------------------
__global__ __launch_bounds__(256) void k_gemm_neigh(
    const __hip_bfloat16* __restrict__ A,   // T  [4096][4096]
    const __hip_bfloat16* __restrict__ BT,  // adjT [4096][4096]
    float* __restrict__ out)                // holds U; RMW + relu
{
    __shared__ alignas(16) __hip_bfloat16 As[128 * 32];
    __shared__ alignas(16) __hip_bfloat16 Bs[128 * 32];

    const int tid   = threadIdx.x;
    const int lane  = tid & 63;
    const int wave  = tid >> 6;
    const int bm    = blockIdx.y << 7;
    const int bn    = blockIdx.x << 7;
    const int waveM = (wave >> 1) << 6;
    const int waveN = (wave & 1) << 6;
    const int lr    = lane & 15;   // row (A) / col (B) within 16-tile
    const int lq    = lane >> 4;   // k-quad

    f32x4 acc[4][4] = {};

    const int r0 = tid >> 2;
    const int c0 = (tid & 3) << 3;
    const __hip_bfloat16* ga = A  + (size_t)(bm + r0) * 4096 + c0;
    const __hip_bfloat16* gb = BT + (size_t)(bn + r0) * 4096 + c0;
    char* la = (char*)As + tid * 16;
    char* lb = (char*)Bs + tid * 16;

    for (int k0 = 0; k0 < 4096; k0 += 32) {
        async_copy16(ga + k0,                     la);
        async_copy16(ga + (size_t)64 * 4096 + k0, la + 4096);
        async_copy16(gb + k0,                     lb);
        async_copy16(gb + (size_t)64 * 4096 + k0, lb + 4096);
        __syncthreads();

        bf16x8 af[4], bfr[4];
#pragma unroll
        for (int t = 0; t < 4; ++t) {
            af[t]  = *(const bf16x8*)&As[(waveM + t * 16 + lr) * 32 + lq * 8];
            bfr[t] = *(const bf16x8*)&Bs[(waveN + t * 16 + lr) * 32 + lq * 8];
        }
#pragma unroll
        for (int tm = 0; tm < 4; ++tm)
#pragma unroll
            for (int tn = 0; tn < 4; ++tn)
                acc[tm][tn] = __builtin_amdgcn_mfma_f32_16x16x32_bf16(
                    af[tm], bfr[tn], acc[tm][tn], 0, 0, 0);
        __syncthreads();
    }

    // epilogue: C/D col=lane&15 (=j), row=quad*4+reg (=m); q=m&31 contiguous
#pragma unroll
    for (int tm = 0; tm < 4; ++tm) {
        const int gm0 = bm + waveM + tm * 16 + lq * 4;
        const int b   = gm0 >> 5;
        const int q0  = gm0 & 31;
#pragma unroll
        for (int tn = 0; tn < 4; ++tn) {
            const int gj = bn + waveN + tn * 16 + lr;
            float* p = out + (size_t)b * (N_NODES * DD) + (size_t)gj * DD + q0;
            const float4 u = *(const float4*)p;
            float4 v;
            v.x = fmaxf(acc[tm][tn][0] + u.x, 0.0f);
            v.y = fmaxf(acc[tm][tn][1] + u.y, 0.0f);
            v.z = fmaxf(acc[tm][tn][2] + u.z, 0.0f);
            v.w = fmaxf(acc[tm][tn][3] + u.w, 0.0f);
            *(float4*)p = v;
        }
    }
}

extern "C" void kernel_launch(void* const* d_in, const int* in_sizes, int n_in,
                              void* d_out, int out_size, void* d_ws, size_t ws_size,
                              hipStream_t stream) {
    const float* x   = (const float*)d_in[0];  // [128, 4096*32]
    const float* adj = (const float*)d_in[1];  // [4096, 4096]
    const float* Wn  = (const float*)d_in[2];  // [32, 32]
    const float* Ws  = (const float*)d_in[3];  // [32, 32]
    float* out = (float*)d_out;                // [128, 4096*32]

    __hip_bfloat16* T    = (__hip_bfloat16*)d_ws;
    __hip_bfloat16* adjT = T + (size_t)N_NODES * N_NODES;

    hipLaunchKernelGGL(k_prep, dim3(1024), dim3(256), 0, stream, x, Wn, Ws, T, out);
    hipLaunchKernelGGL(k_transpose_adj, dim3(64, 64), dim3(256), 0, stream, adj, adjT);
    hipLaunchKernelGGL(k_gemm_neigh, dim3(32, 32), dim3(256), 0, stream, T, adjT, out);
}

// Round 3
// 291.912 us; speedup vs baseline: 1.3746x; 1.2610x over previous
//
#include <hip/hip_runtime.h>
#include <hip/hip_bf16.h>

// Problem constants
#define N_NODES 4096
#define BATCH   128
#define DD      32           // D_IN == D_OUT

typedef float  f32x4  __attribute__((ext_vector_type(4)));
typedef __bf16 bf16x8 __attribute__((ext_vector_type(8)));
typedef int    i32x8  __attribute__((ext_vector_type(8)));

// async global->LDS, 16 B per lane. LDS dest semantics: wave-uniform base + lane*16.
__device__ __forceinline__ void async_copy16(const void* g, void* l) {
    __builtin_amdgcn_global_load_lds(
        (const __attribute__((address_space(1))) unsigned int*)g,
        (__attribute__((address_space(3))) unsigned int*)l,
        16, 0, 0);
}

// pack 4 floats -> 4 fp8 e4m3 bytes (OCP), one dword
__device__ __forceinline__ unsigned pack_fp8x4(float a, float b, float c, float d) {
    int v = __builtin_amdgcn_cvt_pk_fp8_f32(a, b, 0, false);   // bytes 0,1
    v     = __builtin_amdgcn_cvt_pk_fp8_f32(c, d, v, true);    // bytes 2,3
    return (unsigned)v;
}

// ---------------------------------------------------------------------------
// Kernel 1 (MFMA): per 16-row tile of x3 [524288 x 32]:
//   T8[m=(b*32+q)][i] = fp8( x @ Wn )   (A operand for the fp8 GEMM)
//   U[b][i][q]        = f32( x @ Ws )   (self part, pre-relu, into d_out)
// ---------------------------------------------------------------------------
__global__ __launch_bounds__(256) void k_prep(
    const float* __restrict__ x, const float* __restrict__ Wn,
    const float* __restrict__ Ws, unsigned char* __restrict__ T8,
    float* __restrict__ out)
{
    const int lane = threadIdx.x & 63;
    const int gw   = (blockIdx.x * 256 + threadIdx.x) >> 6;  // global wave id, 0..8191
    const int m    = lane & 15;   // A row / C col index
    const int quad = lane >> 4;   // k-quad

    // B fragments: Bt[n][k] with n=lane&15, k=quad*8+j  ->  W[k*32+n]
    bf16x8 bn[2], bs[2];
#pragma unroll
    for (int h = 0; h < 2; ++h) {
        const int n = m + h * 16;
#pragma unroll
        for (int j = 0; j < 8; ++j) {
            const int k = quad * 8 + j;
            bn[h][j] = (__bf16)Wn[k * 32 + n];
            bs[h][j] = (__bf16)Ws[k * 32 + n];
        }
    }

    for (int t = gw; t < 32768; t += 8192) {       // 16-row tiles, 4 iters/wave
        const int row0 = t << 4;                   // global row = b*4096 + i0
        const int b    = row0 >> 12;
        const int i0   = row0 & 4095;

        const float4* xp = (const float4*)(x + (size_t)(row0 + m) * DD + quad * 8);
        const float4 x0 = xp[0], x1 = xp[1];
        bf16x8 a;
        a[0] = (__bf16)x0.x; a[1] = (__bf16)x0.y; a[2] = (__bf16)x0.z; a[3] = (__bf16)x0.w;
        a[4] = (__bf16)x1.x; a[5] = (__bf16)x1.y; a[6] = (__bf16)x1.z; a[7] = (__bf16)x1.w;

        const f32x4 z = {};
        const f32x4 cT0 = __builtin_amdgcn_mfma_f32_16x16x32_bf16(a, bn[0], z, 0, 0, 0);
        const f32x4 cT1 = __builtin_amdgcn_mfma_f32_16x16x32_bf16(a, bn[1], z, 0, 0, 0);
        const f32x4 cU0 = __builtin_amdgcn_mfma_f32_16x16x32_bf16(a, bs[0], z, 0, 0, 0);
        const f32x4 cU1 = __builtin_amdgcn_mfma_f32_16x16x32_bf16(a, bs[1], z, 0, 0, 0);

        // C/D: col=lane&15 (=q half), row=quad*4+reg (=i-local, 4 consecutive)
        *(unsigned*)&T8[((size_t)(b * 32 + m))      * N_NODES + i0 + quad * 4] =
            pack_fp8x4(cT0[0], cT0[1], cT0[2], cT0[3]);
        *(unsigned*)&T8[((size_t)(b * 32 + m + 16)) * N_NODES + i0 + quad * 4] =
            pack_fp8x4(cT1[0], cT1[1], cT1[2], cT1[3]);

        float* ub = out + (size_t)b * (N_NODES * DD) + (size_t)(i0 + quad * 4) * DD;
#pragma unroll
        for (int r = 0; r < 4; ++r) {           // 64B-aligned full sectors per instr
            ub[r * DD + m]      = cU0[r];
            ub[r * DD + m + 16] = cU1[r];
        }
    }
}

// ---------------------------------------------------------------------------
// Kernel 2: adjT8[j][i] = fp8( adj[i][j] * 4096 )  — the 2^12 scale is removed
// in hardware by the MFMA's B e8m0 scale byte (115 = 2^-12), exact.
// ---------------------------------------------------------------------------
__global__ __launch_bounds__(256) void k_transpose_adj(
    const float* __restrict__ adj, unsigned char* __restrict__ adjT8)
{
    __shared__ float ts[64][65];
    const int tid = threadIdx.x;
    const int cx  = tid & 63;
    const int cy  = tid >> 6;
    const int i0  = blockIdx.y << 6;
    const int j0  = blockIdx.x << 6;
#pragma unroll
    for (int r = 0; r < 16; ++r) {
        const int row = cy * 16 + r;
        ts[row][cx] = adj[(size_t)(i0 + row) * N_NODES + j0 + cx];
    }
    __syncthreads();
    const int il = (tid & 7) * 8;
    const int jb = tid >> 3;          // 0..31
#pragma unroll
    for (int rr = 0; rr < 2; ++rr) {
        const int jl = jb + rr * 32;
        float v[8];
#pragma unroll
        for (int k = 0; k < 8; ++k) v[k] = ts[il + k][jl] * 4096.0f;
        uint2 p;
        p.x = pack_fp8x4(v[0], v[1], v[2], v[3]);
        p.y = pack_fp8x4(v[4], v[5], v[6], v[7]);
        *(uint2*)&adjT8[(size_t)(j0 + jl) * N_NODES + i0 + il] = p;
    }
}

// ---------------------------------------------------------------------------
// Kernel 3: C[m][j] = sum_i T[m][i] * adjT[j][i]  — 4096^3 MX-fp8 GEMM (m148
// structure): 128x128 tile, BK=128 bytes, 4 waves x (4x4) 16x16x128 f8f6f4
// MFMA, global_load_lds width 16. Scales: A=1.0 (127), B=2^-12 (115).
//           out[b*131072 + j*32 + q] = relu(U + C),  m = b*32+q
// ---------------------------------------------------------------------------
__global__ __launch_bounds__(256) void k_gemm_neigh(
    const unsigned char* __restrict__ A8,   // T8   [4096][4096] fp8
    const unsigned char* __restrict__ B8,   // adjT8 [4096][4096] fp8 (x4096)
    float* __restrict__ out)                // holds U; RMW + relu
{
    __shared__ alignas(16) unsigned char As[128 * 128];
    __shared__ alignas(16) unsigned char Bs[128 * 128];

    const int tid   = threadIdx.x;
    const int lane  = tid & 63;
    const int wave  = tid >> 6;
    const int bm    = blockIdx.y << 7;
    const int bn    = blockIdx.x << 7;
    const int waveM = (wave >> 1) << 6;
    const int waveN = (wave & 1) << 6;
    const int lr    = lane & 15;   // row (A) / col (B) within 16-tile
    const int lq    = lane >> 4;   // k-chunk (32 bytes each)

    f32x4 acc[4][4] = {};

    // staging: issue n covers rows n*32 + tid/8, bytes (tid&7)*16
    const unsigned char* ga = A8 + (size_t)(bm + (tid >> 3)) * 4096 + (tid & 7) * 16;
    const unsigned char* gb = B8 + (size_t)(bn + (tid >> 3)) * 4096 + (tid & 7) * 16;
    char* la = (char*)As + tid * 16;
    char* lb = (char*)Bs + tid * 16;

    for (int k0 = 0; k0 < 4096; k0 += 128) {
#pragma unroll
        for (int n = 0; n < 4; ++n) {
            async_copy16(ga + (size_t)(n * 32) * 4096 + k0, la + n * 4096);
            async_copy16(gb + (size_t)(n * 32) * 4096 + k0, lb + n * 4096);
        }
        __syncthreads();   // drains vmcnt -> LDS tiles complete

        i32x8 af[4], bfr[4];
#pragma unroll
        for (int t = 0; t < 4; ++t) {
            af[t]  = *(const i32x8*)&As[(waveM + t * 16 + lr) * 128 + lq * 32];
            bfr[t] = *(const i32x8*)&Bs[(waveN + t * 16 + lr) * 128 + lq * 32];
        }
#pragma unroll
        for (int tm = 0; tm < 4; ++tm)
#pragma unroll
            for (int tn = 0; tn < 4; ++tn)
                acc[tm][tn] = __builtin_amdgcn_mfma_scale_f32_16x16x128_f8f6f4(
                    af[tm], bfr[tn], acc[tm][tn],
                    0, 0,              // cbsz=fp8(e4m3), blgp=fp8(e4m3)
                    0, 0x7F,           // A scale: byte0, 2^0
                    0, 0x73);          // B scale: byte0, 2^-12 (undo adj*4096)
        __syncthreads();
    }

    // epilogue: C/D col=lane&15 (=j), row=quad*4+reg (=m); q=m&31 contiguous
#pragma unroll
    for (int tm = 0; tm < 4; ++tm) {
        const int gm0 = bm + waveM + tm * 16 + lq * 4;
        const int b   = gm0 >> 5;
        const int q0  = gm0 & 31;
#pragma unroll
        for (int tn = 0; tn < 4; ++tn) {
            const int gj = bn + waveN + tn * 16 + lr;
            float* p = out + (size_t)b * (N_NODES * DD) + (size_t)gj * DD + q0;
            const float4 u = *(const float4*)p;
            float4 v;
            v.x = fmaxf(acc[tm][tn][0] + u.x, 0.0f);
            v.y = fmaxf(acc[tm][tn][1] + u.y, 0.0f);
            v.z = fmaxf(acc[tm][tn][2] + u.z, 0.0f);
            v.w = fmaxf(acc[tm][tn][3] + u.w, 0.0f);
            *(float4*)p = v;
        }
    }
}

extern "C" void kernel_launch(void* const* d_in, const int* in_sizes, int n_in,
                              void* d_out, int out_size, void* d_ws, size_t ws_size,
                              hipStream_t stream) {
    const float* x   = (const float*)d_in[0];  // [128, 4096*32]
    const float* adj = (const float*)d_in[1];  // [4096, 4096]
    const float* Wn  = (const float*)d_in[2];  // [32, 32]
    const float* Ws  = (const float*)d_in[3];  // [32, 32]
    float* out = (float*)d_out;                // [128, 4096*32]

    // workspace: T8 fp8 (16 MB) | adjT8 fp8 (16 MB)
    unsigned char* T8    = (unsigned char*)d_ws;
    unsigned char* adjT8 = T8 + (size_t)N_NODES * N_NODES;

    hipLaunchKernelGGL(k_prep, dim3(2048), dim3(256), 0, stream, x, Wn, Ws, T8, out);
    hipLaunchKernelGGL(k_transpose_adj, dim3(64, 64), dim3(256), 0, stream, adj, adjT8);
    hipLaunchKernelGGL(k_gemm_neigh, dim3(32, 32), dim3(256), 0, stream, T8, adjT8, out);
}

// Round 4
// 272.968 us; speedup vs baseline: 1.4700x; 1.0694x over previous
//
#include <hip/hip_runtime.h>
#include <hip/hip_bf16.h>

// Problem constants
#define N_NODES 4096
#define BATCH   128
#define DD      32           // D_IN == D_OUT

typedef float  f32x4  __attribute__((ext_vector_type(4)));
typedef __bf16 bf16x8 __attribute__((ext_vector_type(8)));
typedef int    i32x4  __attribute__((ext_vector_type(4)));
typedef int    i32x8  __attribute__((ext_vector_type(8)));

#define PREP_BLOCKS 2048
#define TR_BLOCKS   4096   // 64x64 tiles

// async global->LDS, 16 B per lane. LDS dest must be linear in lane (uniform base + lane*16).
__device__ __forceinline__ void async_copy16(const void* g, void* l) {
    __builtin_amdgcn_global_load_lds(
        (const __attribute__((address_space(1))) unsigned int*)g,
        (__attribute__((address_space(3))) unsigned int*)l,
        16, 0, 0);
}

// pack 4 floats -> 4 fp8 e4m3 bytes (OCP), one dword
__device__ __forceinline__ unsigned pack_fp8x4(float a, float b, float c, float d) {
    int v = __builtin_amdgcn_cvt_pk_fp8_f32(a, b, 0, false);   // bytes 0,1
    v     = __builtin_amdgcn_cvt_pk_fp8_f32(c, d, v, true);    // bytes 2,3
    return (unsigned)v;
}

// ---------------------------------------------------------------------------
// Fused pre-stage. Blocks [0, PREP_BLOCKS): per 16-row tile of x3 [524288 x 32]:
//   T8[m=(b*32+q)][i] = fp8( x @ Wn )   (A operand for the fp8 GEMM)
//   U[b][i][q]        = f32( x @ Ws )   (self part, pre-relu, into d_out)
// Blocks [PREP_BLOCKS, +TR_BLOCKS): adjT8[j][i] = fp8( adj[i][j] * 4096 )
//   (2^12 scale removed exactly by the GEMM's B e8m0 scale byte 0x73)
// ---------------------------------------------------------------------------
__global__ __launch_bounds__(256) void k_pre(
    const float* __restrict__ x, const float* __restrict__ adj,
    const float* __restrict__ Wn, const float* __restrict__ Ws,
    unsigned char* __restrict__ T8, unsigned char* __restrict__ adjT8,
    float* __restrict__ out)
{
    __shared__ float ts[64][65];
    const int tid = threadIdx.x;

    if (blockIdx.x < PREP_BLOCKS) {
        // ---- prep branch (MFMA, no LDS) ----
        const int lane = tid & 63;
        const int gw   = (blockIdx.x * 256 + tid) >> 6;  // wave id 0..8191
        const int m    = lane & 15;   // A row / C col index
        const int quad = lane >> 4;   // k-quad

        // B fragments: Bt[n][k] with n=lane&15, k=quad*8+j  ->  W[k*32+n]
        bf16x8 bn[2], bs[2];
#pragma unroll
        for (int h = 0; h < 2; ++h) {
            const int n = m + h * 16;
#pragma unroll
            for (int j = 0; j < 8; ++j) {
                const int k = quad * 8 + j;
                bn[h][j] = (__bf16)Wn[k * 32 + n];
                bs[h][j] = (__bf16)Ws[k * 32 + n];
            }
        }

        for (int t = gw; t < 32768; t += 8192) {       // 16-row tiles, 4 iters/wave
            const int row0 = t << 4;                   // global row = b*4096 + i0
            const int b    = row0 >> 12;
            const int i0   = row0 & 4095;

            const float4* xp = (const float4*)(x + (size_t)(row0 + m) * DD + quad * 8);
            const float4 x0 = xp[0], x1 = xp[1];
            bf16x8 a;
            a[0] = (__bf16)x0.x; a[1] = (__bf16)x0.y; a[2] = (__bf16)x0.z; a[3] = (__bf16)x0.w;
            a[4] = (__bf16)x1.x; a[5] = (__bf16)x1.y; a[6] = (__bf16)x1.z; a[7] = (__bf16)x1.w;

            const f32x4 z = {};
            const f32x4 cT0 = __builtin_amdgcn_mfma_f32_16x16x32_bf16(a, bn[0], z, 0, 0, 0);
            const f32x4 cT1 = __builtin_amdgcn_mfma_f32_16x16x32_bf16(a, bn[1], z, 0, 0, 0);
            const f32x4 cU0 = __builtin_amdgcn_mfma_f32_16x16x32_bf16(a, bs[0], z, 0, 0, 0);
            const f32x4 cU1 = __builtin_amdgcn_mfma_f32_16x16x32_bf16(a, bs[1], z, 0, 0, 0);

            // C/D: col=lane&15, row=quad*4+reg (i-local, 4 consecutive)
            *(unsigned*)&T8[((size_t)(b * 32 + m))      * N_NODES + i0 + quad * 4] =
                pack_fp8x4(cT0[0], cT0[1], cT0[2], cT0[3]);
            *(unsigned*)&T8[((size_t)(b * 32 + m + 16)) * N_NODES + i0 + quad * 4] =
                pack_fp8x4(cT1[0], cT1[1], cT1[2], cT1[3]);

            float* ub = out + (size_t)b * (N_NODES * DD) + (size_t)(i0 + quad * 4) * DD;
#pragma unroll
            for (int r = 0; r < 4; ++r) {   // full 64B sectors per instr
                ub[r * DD + m]      = cU0[r];
                ub[r * DD + m + 16] = cU1[r];
            }
        }
    } else {
        // ---- transpose branch ----
        const int bid = blockIdx.x - PREP_BLOCKS;
        const int cx  = tid & 63;
        const int cy  = tid >> 6;
        const int i0  = (bid >> 6) << 6;
        const int j0  = (bid & 63) << 6;
#pragma unroll
        for (int r = 0; r < 16; ++r) {
            const int row = cy * 16 + r;
            ts[row][cx] = adj[(size_t)(i0 + row) * N_NODES + j0 + cx];
        }
        __syncthreads();
        const int il = (tid & 7) * 8;
        const int jb = tid >> 3;          // 0..31
#pragma unroll
        for (int rr = 0; rr < 2; ++rr) {
            const int jl = jb + rr * 32;
            float v[8];
#pragma unroll
            for (int k = 0; k < 8; ++k) v[k] = ts[il + k][jl] * 4096.0f;
            uint2 p;
            p.x = pack_fp8x4(v[0], v[1], v[2], v[3]);
            p.y = pack_fp8x4(v[4], v[5], v[6], v[7]);
            *(uint2*)&adjT8[(size_t)(j0 + jl) * N_NODES + i0 + il] = p;
        }
    }
}

// ---------------------------------------------------------------------------
// GEMM: C[m][j] = sum_i T[m][i]*adjT[j][i] — 4096^3 MX-fp8, 128x128 tile,
// BK=128B, 4 waves x (4x4) 16x16x128 f8f6f4 MFMA, global_load_lds width 16.
// LDS is XOR-swizzled AT STAGING TIME: global 16B chunk (r, c16) lands at LDS
// chunk (r, c16 ^ (r&7)).  Read side: chunk ((2*lq+h) ^ (lr&7)) -> every
// 8-lane phase covers all 8 bank-quads -> conflict-free ds_read_b128.
//           out[b*131072 + j*32 + q] = relu(U + C),  m = b*32+q
// ---------------------------------------------------------------------------
__global__ __launch_bounds__(256) void k_gemm_neigh(
    const unsigned char* __restrict__ A8,   // T8    [4096][4096] fp8
    const unsigned char* __restrict__ B8,   // adjT8 [4096][4096] fp8 (x4096)
    float* __restrict__ out)                // holds U; RMW + relu
{
    __shared__ alignas(16) unsigned char As[128 * 128];
    __shared__ alignas(16) unsigned char Bs[128 * 128];

    const int tid   = threadIdx.x;
    const int lane  = tid & 63;
    const int wave  = tid >> 6;
    const int bm    = blockIdx.y << 7;
    const int bn    = blockIdx.x << 7;
    const int waveM = (wave >> 1) << 6;
    const int waveN = (wave & 1) << 6;
    const int lr    = lane & 15;   // row (A) / col (B) within 16-tile
    const int lq    = lane >> 4;   // k-chunk (32 bytes)
    const int sw    = lr & 7;      // read-side XOR swizzle

    f32x4 acc[4][4] = {};

    // staging: row r = tid>>3 (+n*32); source chunk swizzled by r&7 so the
    // LDS image at (r, c16) holds global chunk c16 ^ (r&7)
    const int srow = tid >> 3;
    const int scol = ((tid & 7) ^ (srow & 7)) * 16;
    const unsigned char* ga = A8 + (size_t)(bm + srow) * 4096 + scol;
    const unsigned char* gb = B8 + (size_t)(bn + srow) * 4096 + scol;
    char* la = (char*)As + tid * 16;
    char* lb = (char*)Bs + tid * 16;

    for (int k0 = 0; k0 < 4096; k0 += 128) {
#pragma unroll
        for (int n = 0; n < 4; ++n) {
            async_copy16(ga + (size_t)(n * 32) * 4096 + k0, la + n * 4096);
            async_copy16(gb + (size_t)(n * 32) * 4096 + k0, lb + n * 4096);
        }
        __syncthreads();   // drains vmcnt -> LDS tiles complete

        i32x8 af[4], bfr[4];
#pragma unroll
        for (int t = 0; t < 4; ++t) {
            const int ra = (waveM + t * 16 + lr) * 128;
            const int rb = (waveN + t * 16 + lr) * 128;
            const int c0 = ((2 * lq)     ^ sw) * 16;
            const int c1 = ((2 * lq + 1) ^ sw) * 16;
            const i32x4 alo = *(const i32x4*)&As[ra + c0];
            const i32x4 ahi = *(const i32x4*)&As[ra + c1];
            const i32x4 blo = *(const i32x4*)&Bs[rb + c0];
            const i32x4 bhi = *(const i32x4*)&Bs[rb + c1];
            af[t][0]=alo[0]; af[t][1]=alo[1]; af[t][2]=alo[2]; af[t][3]=alo[3];
            af[t][4]=ahi[0]; af[t][5]=ahi[1]; af[t][6]=ahi[2]; af[t][7]=ahi[3];
            bfr[t][0]=blo[0]; bfr[t][1]=blo[1]; bfr[t][2]=blo[2]; bfr[t][3]=blo[3];
            bfr[t][4]=bhi[0]; bfr[t][5]=bhi[1]; bfr[t][6]=bhi[2]; bfr[t][7]=bhi[3];
        }
#pragma unroll
        for (int tm = 0; tm < 4; ++tm)
#pragma unroll
            for (int tn = 0; tn < 4; ++tn)
                acc[tm][tn] = __builtin_amdgcn_mfma_scale_f32_16x16x128_f8f6f4(
                    af[tm], bfr[tn], acc[tm][tn],
                    0, 0,              // cbsz=fp8(e4m3), blgp=fp8(e4m3)
                    0, 0x7F,           // A scale: 2^0
                    0, 0x73);          // B scale: 2^-12 (undo adj*4096)
        __syncthreads();
    }

    // epilogue: C/D col=lane&15 (=j), row=quad*4+reg (=m); q=m&31 contiguous
#pragma unroll
    for (int tm = 0; tm < 4; ++tm) {
        const int gm0 = bm + waveM + tm * 16 + lq * 4;
        const int b   = gm0 >> 5;
        const int q0  = gm0 & 31;
#pragma unroll
        for (int tn = 0; tn < 4; ++tn) {
            const int gj = bn + waveN + tn * 16 + lr;
            float* p = out + (size_t)b * (N_NODES * DD) + (size_t)gj * DD + q0;
            const float4 u = *(const float4*)p;
            float4 v;
            v.x = fmaxf(acc[tm][tn][0] + u.x, 0.0f);
            v.y = fmaxf(acc[tm][tn][1] + u.y, 0.0f);
            v.z = fmaxf(acc[tm][tn][2] + u.z, 0.0f);
            v.w = fmaxf(acc[tm][tn][3] + u.w, 0.0f);
            *(float4*)p = v;
        }
    }
}

extern "C" void kernel_launch(void* const* d_in, const int* in_sizes, int n_in,
                              void* d_out, int out_size, void* d_ws, size_t ws_size,
                              hipStream_t stream) {
    const float* x   = (const float*)d_in[0];  // [128, 4096*32]
    const float* adj = (const float*)d_in[1];  // [4096, 4096]
    const float* Wn  = (const float*)d_in[2];  // [32, 32]
    const float* Ws  = (const float*)d_in[3];  // [32, 32]
    float* out = (float*)d_out;                // [128, 4096*32]

    // workspace: T8 fp8 (16 MB) | adjT8 fp8 (16 MB)
    unsigned char* T8    = (unsigned char*)d_ws;
    unsigned char* adjT8 = T8 + (size_t)N_NODES * N_NODES;

    hipLaunchKernelGGL(k_pre, dim3(PREP_BLOCKS + TR_BLOCKS), dim3(256), 0, stream,
                       x, adj, Wn, Ws, T8, adjT8, out);
    hipLaunchKernelGGL(k_gemm_neigh, dim3(32, 32), dim3(256), 0, stream, T8, adjT8, out);
}